// Round 2
// baseline (134.277 us; speedup 1.0000x reference)
//
#include <hip/hip_runtime.h>

#define NB 2048
#define SA 121
#define EMB_TOTAL (NB * 64 * SA)   // 15,859,712 floats

typedef short bf16x8 __attribute__((ext_vector_type(8)));
typedef float f32x4  __attribute__((ext_vector_type(4)));

__device__ __forceinline__ short f2bf(float f) {
    union { float f; unsigned u; } v; v.f = f;
    unsigned r = (v.u + 0x7fffu + ((v.u >> 16) & 1u)) >> 16;
    return (short)r;
}
__device__ __forceinline__ float bf2f(short s) {
    union { unsigned u; float f; } v; v.u = ((unsigned)(unsigned short)s) << 16;
    return v.f;
}

// Convert f32 weights -> zero-padded bf16 copies in workspace.
// ws layout (shorts): WQ[128*128] @0, WK @16384, WV @32768, WC[64*128] @49152
__global__ void convert_weights(const float* __restrict__ Wq, const float* __restrict__ Wk,
                                const float* __restrict__ Wv, const float* __restrict__ Wc,
                                short* __restrict__ ws) {
    int i = blockIdx.x * 256 + threadIdx.x;   // 0 .. 57343
    if (i < 49152) {
        int m = i / 16384;
        const float* W = (m == 0) ? Wq : ((m == 1) ? Wk : Wv);
        int j = i & 16383;
        int r = j >> 7, c = j & 127;
        float v = (r < SA && c < SA) ? W[r * SA + c] : 0.f;
        ws[i] = f2bf(v);
    } else {
        int j = i - 49152;                    // Wc is exactly [64][128]
        ws[i] = f2bf(Wc[j]);
    }
}

__launch_bounds__(256, 2)
__global__ void fused_kernel(const float* __restrict__ lidar, const float* __restrict__ hsi,
                             const float* __restrict__ bq, const float* __restrict__ bk,
                             const float* __restrict__ bv,
                             const float* __restrict__ Wr1, const float* __restrict__ br1,
                             const float* __restrict__ Wr2, const float* __restrict__ br2,
                             const float* __restrict__ bc,
                             const short* __restrict__ wsb, float* __restrict__ out) {
    // LDS: all bf16 (short). strides: 136 (128-col bufs), 72 (64-col bufs)
    __shared__ __align__(16) short sA[64 * 136];   // lidar
    __shared__ __align__(16) short sB[64 * 136];   // hsi
    __shared__ __align__(16) short sC[64 * 136];   // q
    __shared__ __align__(16) short sD[128 * 72];   // k (as [64][136]) then G^T [128][72]
    __shared__ __align__(16) short sE[64 * 72];    // P^T then M
    __shared__ float sR[264];                      // router scratch

    const int tid  = threadIdx.x;
    const int b    = blockIdx.x;
    const int lane = tid & 63;
    const int wid  = tid >> 6;
    const int l16  = lane & 15;
    const int g16  = lane >> 4;

    const short* WQ = wsb;
    const short* WK = wsb + 16384;
    const short* WV = wsb + 32768;
    const short* WC = wsb + 49152;

    // ---- stage inputs (f32 -> bf16 LDS) ----
    const float* gl = lidar + (size_t)b * 7744;
    const float* gh = hsi   + (size_t)b * 7744;
    for (int i = tid; i < 7744; i += 256) {
        int r = i / 121, c = i - r * 121;
        sA[r * 136 + c] = f2bf(gl[i]);
        sB[r * 136 + c] = f2bf(gh[i]);
    }
    // zero pad cols 121..127 (K padding must be 0; 448 elems > 256 threads -> loop!)
    for (int i = tid; i < 448; i += 256) {
        int r = i / 7, c = 121 + i % 7;
        sA[r * 136 + c] = 0;
        sB[r * 136 + c] = 0;
    }
    __syncthreads();

    // ---- router ----
    if (tid < 128) {
        const short* row = (tid < 64) ? (sA + tid * 136) : (sB + (tid - 64) * 136);
        float s = 0.f;
        for (int j = 0; j < 121; ++j) s += bf2f(row[j]);
        sR[tid] = s * (1.f / 121.f);
    }
    __syncthreads();
    if (tid < 128) {
        float a = br1[tid];
        for (int c = 0; c < 128; ++c) a += sR[c] * Wr1[c * 128 + tid];
        sR[128 + tid] = fmaxf(a, 0.f);
    }
    __syncthreads();
    if (tid < 4) {
        float a = br2[tid];
        for (int h = 0; h < 128; ++h) a += sR[128 + h] * Wr2[h * 4 + tid];
        sR[256 + tid] = a;
    }
    __syncthreads();
    if (tid < 4) {
        float m = fmaxf(fmaxf(sR[256], sR[257]), fmaxf(sR[258], sR[259]));
        float e = __expf(sR[256 + tid] - m);
        float s = 0.f;
        for (int p = 0; p < 4; ++p) s += __expf(sR[256 + p] - m);
        out[EMB_TOTAL + b * 4 + tid] = e / s;
    }

    f32x4 eacc[8];
    #pragma unroll
    for (int n = 0; n < 8; ++n) eacc[n] = (f32x4){0.f, 0.f, 0.f, 0.f};

    #pragma unroll 1
    for (int dir = 0; dir < 2; ++dir) {
        const short* Xqk = dir ? sB : sA;
        const short* Xv  = dir ? sA : sB;
        const int colbase = dir ? 0 : 64;   // Wc column block: dir0->h_emb (cols 64:), dir1->l_emb (cols :64)

        // ---- q -> sC, k -> sD (both [64][136]) ----
        #pragma unroll 1
        for (int which = 0; which < 2; ++which) {
            const short* W    = which ? WK : WQ;
            const float* bias = which ? bk : bq;
            short* OUT        = which ? sD : sC;
            f32x4 acc[4][2];
            #pragma unroll
            for (int m = 0; m < 4; ++m) { acc[m][0] = (f32x4){0,0,0,0}; acc[m][1] = (f32x4){0,0,0,0}; }
            #pragma unroll
            for (int k0 = 0; k0 < 128; k0 += 32) {
                bf16x8 bfr[2];
                #pragma unroll
                for (int nn = 0; nn < 2; ++nn) {
                    int n0 = (2 * wid + nn) * 16;
                    bfr[nn] = *(const bf16x8*)&W[(n0 + l16) * 128 + k0 + g16 * 8];
                }
                #pragma unroll
                for (int m = 0; m < 4; ++m) {
                    bf16x8 afr = *(const bf16x8*)&Xqk[(m * 16 + l16) * 136 + k0 + g16 * 8];
                    acc[m][0] = __builtin_amdgcn_mfma_f32_16x16x32_bf16(afr, bfr[0], acc[m][0], 0, 0, 0);
                    acc[m][1] = __builtin_amdgcn_mfma_f32_16x16x32_bf16(afr, bfr[1], acc[m][1], 0, 0, 0);
                }
            }
            #pragma unroll
            for (int nn = 0; nn < 2; ++nn) {
                int sc_ = (2 * wid + nn) * 16 + l16;
                float bvv = (sc_ < SA) ? bias[sc_] : 0.f;
                #pragma unroll
                for (int m = 0; m < 4; ++m)
                    #pragma unroll
                    for (int r = 0; r < 4; ++r) {
                        int row = m * 16 + g16 * 4 + r;
                        OUT[row * 136 + sc_] = f2bf(acc[m][nn][r] + bvv);
                    }
            }
        }
        __syncthreads();

        // ---- scores = q @ k^T, softmax over g, write P^T to sE ----
        {
            f32x4 sc[4];
            #pragma unroll
            for (int n = 0; n < 4; ++n) sc[n] = (f32x4){0,0,0,0};
            #pragma unroll
            for (int k0 = 0; k0 < 128; k0 += 32) {
                bf16x8 afr = *(const bf16x8*)&sC[(wid * 16 + l16) * 136 + k0 + g16 * 8];
                #pragma unroll
                for (int n = 0; n < 4; ++n) {
                    bf16x8 bfr = *(const bf16x8*)&sD[(n * 16 + l16) * 136 + k0 + g16 * 8];
                    sc[n] = __builtin_amdgcn_mfma_f32_16x16x32_bf16(afr, bfr, sc[n], 0, 0, 0);
                }
            }
            #pragma unroll
            for (int r = 0; r < 4; ++r) {
                float mx = fmaxf(fmaxf(sc[0][r], sc[1][r]), fmaxf(sc[2][r], sc[3][r]));
                #pragma unroll
                for (int off = 1; off < 16; off <<= 1) mx = fmaxf(mx, __shfl_xor(mx, off, 64));
                float e0 = exp2f((sc[0][r] - mx) * 1.44269504f);
                float e1 = exp2f((sc[1][r] - mx) * 1.44269504f);
                float e2 = exp2f((sc[2][r] - mx) * 1.44269504f);
                float e3 = exp2f((sc[3][r] - mx) * 1.44269504f);
                float sum = e0 + e1 + e2 + e3;
                #pragma unroll
                for (int off = 1; off < 16; off <<= 1) sum += __shfl_xor(sum, off, 64);
                float inv = 1.f / sum;
                int crow = wid * 16 + g16 * 4 + r;
                sE[(0 * 16 + l16) * 72 + crow] = f2bf(e0 * inv);
                sE[(1 * 16 + l16) * 72 + crow] = f2bf(e1 * inv);
                sE[(2 * 16 + l16) * 72 + crow] = f2bf(e2 * inv);
                sE[(3 * 16 + l16) * 72 + crow] = f2bf(e3 * inv);
            }
        }
        __syncthreads();

        // ---- v-proj -> G^T = (q .* v)^T into sD[128][72]; M = Wc_part @ P (regs) ----
        {
            f32x4 acc[4][2];
            #pragma unroll
            for (int m = 0; m < 4; ++m) { acc[m][0] = (f32x4){0,0,0,0}; acc[m][1] = (f32x4){0,0,0,0}; }
            #pragma unroll
            for (int k0 = 0; k0 < 128; k0 += 32) {
                bf16x8 bfr[2];
                #pragma unroll
                for (int nn = 0; nn < 2; ++nn) {
                    int n0 = (2 * wid + nn) * 16;
                    bfr[nn] = *(const bf16x8*)&WV[(n0 + l16) * 128 + k0 + g16 * 8];
                }
                #pragma unroll
                for (int m = 0; m < 4; ++m) {
                    bf16x8 afr = *(const bf16x8*)&Xv[(m * 16 + l16) * 136 + k0 + g16 * 8];
                    acc[m][0] = __builtin_amdgcn_mfma_f32_16x16x32_bf16(afr, bfr[0], acc[m][0], 0, 0, 0);
                    acc[m][1] = __builtin_amdgcn_mfma_f32_16x16x32_bf16(afr, bfr[1], acc[m][1], 0, 0, 0);
                }
            }
            #pragma unroll
            for (int nn = 0; nn < 2; ++nn) {
                int sc_ = (2 * wid + nn) * 16 + l16;
                float bvv = (sc_ < SA) ? bv[sc_] : 0.f;
                #pragma unroll
                for (int m = 0; m < 4; ++m)
                    #pragma unroll
                    for (int r = 0; r < 4; ++r) {
                        int row = m * 16 + g16 * 4 + r;
                        float qv = bf2f(sC[row * 136 + sc_]);
                        sD[sc_ * 72 + row] = f2bf((acc[m][nn][r] + bvv) * qv);
                    }
            }
            // M = Wc[:, colbase:colbase+64] @ P   (reads P^T in sE, all waves)
            f32x4 macc[4];
            #pragma unroll
            for (int n = 0; n < 4; ++n) macc[n] = (f32x4){0,0,0,0};
            #pragma unroll
            for (int k0 = 0; k0 < 64; k0 += 32) {
                bf16x8 afr = *(const bf16x8*)&WC[(wid * 16 + l16) * 128 + colbase + k0 + g16 * 8];
                #pragma unroll
                for (int n = 0; n < 4; ++n) {
                    bf16x8 bfr = *(const bf16x8*)&sE[(n * 16 + l16) * 72 + k0 + g16 * 8];
                    macc[n] = __builtin_amdgcn_mfma_f32_16x16x32_bf16(afr, bfr, macc[n], 0, 0, 0);
                }
            }
            __syncthreads();   // all P^T reads done, all G^T writes done
            #pragma unroll
            for (int n = 0; n < 4; ++n)
                #pragma unroll
                for (int r = 0; r < 4; ++r) {
                    int o = wid * 16 + g16 * 4 + r;
                    sE[o * 72 + n * 16 + l16] = f2bf(macc[n][r]);
                }
        }
        __syncthreads();

        // ---- emb += M @ G   (A = sE [64][72], B = G^T rows in sD [128][72]) ----
        #pragma unroll
        for (int k0 = 0; k0 < 64; k0 += 32) {
            bf16x8 afr = *(const bf16x8*)&sE[(wid * 16 + l16) * 72 + k0 + g16 * 8];
            #pragma unroll
            for (int n = 0; n < 8; ++n) {
                bf16x8 bfr = *(const bf16x8*)&sD[(n * 16 + l16) * 72 + k0 + g16 * 8];
                eacc[n] = __builtin_amdgcn_mfma_f32_16x16x32_bf16(afr, bfr, eacc[n], 0, 0, 0);
            }
        }
        __syncthreads();   // protect sC/sD/sE for next direction
    }

    // ---- epilogue: emb + bc -> global ----
    float* eo = out + (size_t)b * 7744;
    #pragma unroll
    for (int n = 0; n < 8; ++n) {
        int s = n * 16 + l16;
        if (s < SA) {
            #pragma unroll
            for (int r = 0; r < 4; ++r) {
                int o = wid * 16 + g16 * 4 + r;
                eo[o * 121 + s] = eacc[n][r] + bc[o];
            }
        }
    }
}

extern "C" void kernel_launch(void* const* d_in, const int* in_sizes, int n_in,
                              void* d_out, int out_size, void* d_ws, size_t ws_size,
                              hipStream_t stream) {
    const float* lidar = (const float*)d_in[0];
    const float* hsi   = (const float*)d_in[1];
    const float* Wq  = (const float*)d_in[2];  const float* bq  = (const float*)d_in[3];
    const float* Wk  = (const float*)d_in[4];  const float* bk  = (const float*)d_in[5];
    const float* Wv  = (const float*)d_in[6];  const float* bv  = (const float*)d_in[7];
    const float* Wr1 = (const float*)d_in[8];  const float* br1 = (const float*)d_in[9];
    const float* Wr2 = (const float*)d_in[10]; const float* br2 = (const float*)d_in[11];
    const float* Wc  = (const float*)d_in[12]; const float* bc  = (const float*)d_in[13];
    short* wsb = (short*)d_ws;
    float* out = (float*)d_out;

    hipLaunchKernelGGL(convert_weights, dim3(224), dim3(256), 0, stream, Wq, Wk, Wv, Wc, wsb);
    hipLaunchKernelGGL(fused_kernel, dim3(NB), dim3(256), 0, stream,
                       lidar, hsi, bq, bk, bv, Wr1, br1, Wr2, br2, bc, wsb, out);
}